// Round 12
// baseline (852.256 us; speedup 1.0000x reference)
//
#include <hip/hip_runtime.h>

typedef unsigned short u16;
typedef short bf16x8 __attribute__((ext_vector_type(8)));
typedef u16 u16x8 __attribute__((ext_vector_type(8)));
typedef float f32x4 __attribute__((ext_vector_type(4)));

__device__ __forceinline__ float bf2f(u16 u) {
    union { unsigned u; float f; } c; c.u = ((unsigned)u) << 16; return c.f;
}
__device__ __forceinline__ u16 f2bf(float f) {
    union { float f; unsigned u; } c; c.f = f;
    unsigned r = c.u + 0x7FFFu + ((c.u >> 16) & 1u);
    return (u16)(r >> 16);
}
__device__ __forceinline__ float tanh_fast(float x) {
    float e = __expf(2.0f * x);
    return 1.0f - 2.0f / (e + 1.0f);
}
__device__ __forceinline__ void gll16(const void* g, void* l) {
    __builtin_amdgcn_global_load_lds((const __attribute__((address_space(1))) void*)g,
                                     (__attribute__((address_space(3))) void*)l, 16, 0, 0);
}

#define BAR() __builtin_amdgcn_s_barrier()

// ---------------- f32 -> bf16 convert, 8 elems/thread ----------------
__global__ __launch_bounds__(256) void cvt_f32_bf16(const float* __restrict__ src,
                                                    u16* __restrict__ dst, int n8) {
    int i = blockIdx.x * blockDim.x + threadIdx.x;
    int stride = gridDim.x * blockDim.x;
    for (; i < n8; i += stride) {
        const float4* s = (const float4*)(src + (size_t)i * 8);
        float4 a = s[0], b = s[1];
        u16x8 o;
        o[0] = f2bf(a.x); o[1] = f2bf(a.y); o[2] = f2bf(a.z); o[3] = f2bf(a.w);
        o[4] = f2bf(b.x); o[5] = f2bf(b.y); o[6] = f2bf(b.z); o[7] = f2bf(b.w);
        *(u16x8*)(dst + (size_t)i * 8) = o;
    }
}

// ---------------- mq = tanh(Wm @ m_q + bm), one wave per output ----------------
__global__ __launch_bounds__(256) void mq_kernel(const float* __restrict__ Wm,
                                                 const float* __restrict__ q,
                                                 const float* __restrict__ bm,
                                                 float* __restrict__ mq, int D) {
    int w = threadIdx.x >> 6, l = threadIdx.x & 63;
    int e = blockIdx.x * 4 + w;
    const float* wp = Wm + (size_t)e * D;
    float s = 0.f;
    for (int j = 0; j < D; j += 256) {
        float4 wv = *(const float4*)(wp + j + l * 4);
        float4 qv = *(const float4*)(q + j + l * 4);
        s += wv.x * qv.x + wv.y * qv.y + wv.z * qv.z + wv.w * qv.w;
    }
    #pragma unroll
    for (int o = 32; o >= 1; o >>= 1) s += __shfl_xor(s, o);
    if (l == 0) mq[e] = tanh_fast(s + bm[e]);
}

// ---- C[M,N] = A[M,K] @ B[N,K]^T : 128x128, BK=32, 32 KiB LDS -> 4 blocks/CU ----
// 4 waves (2M x 2N, 64x64/wave). LDS: A slots {0,8K}, B slots {16K,24K}.
// Swizzle (64B rows, 4 x 16B slots): phys slot = ks ^ ((row>>1)&3) -- 8 row-pairs
// x 4 slots = 32 banks, 2 lanes/bank (free). Pre-swizzled global src, linear DMA dest.
//   ph1: 8 ds_read (slot t&1) ; lgkmcnt(0) ; BAR    (reads retired -> DMA-safe)
//   ph2: STG(t+2 -> slot t&1, 4 gll16) ; 16 MFMA ; vmcnt(4) retires t+1 ; BAR
// Cross-block overlap at 16 waves/CU hides per-block read/barrier windows.
// EPI=0: C = bf16( tanh(acc+bias[col]) * gate[col] );  EPI=1: C = bf16(acc+bias[col])
template <int EPI>
__global__ __launch_bounds__(256, 4) void gemm_hi(const u16* __restrict__ A,
                                                  const u16* __restrict__ B,
                                                  const float* __restrict__ bias,
                                                  const float* __restrict__ gate,
                                                  u16* __restrict__ C,
                                                  int M, int N, int K) {
    __shared__ u16 sh[16384];            // 32 KiB
    char* LDS = (char*)sh;
    const int K2 = K * 2;
    const int KT = K >> 5;               // K-tiles of 32 (64 here, even)

    const int tid = threadIdx.x;
    const int w = tid >> 6, l = tid & 63;
    const int wm = w >> 1, wn = w & 1;

    // XCD-aware swizzle (nwg = 4096, divisible by 8)
    int orig = blockIdx.x + gridDim.x * blockIdx.y;
    int nwg = gridDim.x * gridDim.y;
    int id = ((nwg & 7) == 0) ? ((orig & 7) * (nwg >> 3) + (orig >> 3)) : orig;
    const int tileN = (id % gridDim.x) * 128;
    const int tileM = (id / gridDim.x) * 128;

    // ---- staging: pass p covers rows p*64 + w*16 + (l>>2); phys slot = l&3;
    // logical ks = (l&3) ^ ((l>>3)&3)  (== phys ^ ((row>>1)&3), w*8 & 3 == 0)
    const int srow = w * 16 + (l >> 2);
    const int cc = ((l & 3) ^ ((l >> 3) & 3)) << 4;
    const char* sAr = (const char*)A + (size_t)(tileM + srow) * K2 + cc;
    const char* sBr = (const char*)B + (size_t)(tileN + srow) * K2 + cc;
    char* dA = LDS + w * 1024;           // + slot*8192 + pass*4096
    char* dB = LDS + 16384 + w * 1024;
    const size_t rowStep = (size_t)64 * K2;

#define STG(tk) do { size_t go = (size_t)(tk) * 64; int sb = ((tk) & 1) * 8192;  \
    gll16(sAr + go, dA + sb);  gll16(sAr + go + rowStep, dA + sb + 4096);        \
    gll16(sBr + go, dB + sb);  gll16(sBr + go + rowStep, dB + sb + 4096); } while (0)

    // ---- reader: frag row = {wm,wn}*64 + fm*16 + (l&15); ks = l>>4;
    // phys = ks ^ (((l&15)>>1)&3)  (fm*16, wm*64 contribute 0 mod 4 after >>1)
    const int rloc = l & 15;
    const int ph = ((l >> 4) ^ ((rloc >> 1) & 3)) << 4;
    const char* pA = LDS + (wm * 64 + rloc) * 64 + ph;           // + slot*8192 + fm*1024
    const char* pB = LDS + 16384 + (wn * 64 + rloc) * 64 + ph;

    f32x4 acc[4][4] = {};

    // ---- prologue: stage tiles 0,1; retire tile0's 4 loads ----
    STG(0); STG(1);
    asm volatile("s_waitcnt vmcnt(4)" ::: "memory");
    BAR();

#define ITER(t, P) do {                                                         \
    constexpr int SL = (P) * 8192;                                              \
    bf16x8 af[4], bf[4];                                                        \
    _Pragma("unroll")                                                           \
    for (int fm = 0; fm < 4; ++fm)                                              \
        af[fm] = *(const bf16x8*)(pA + SL + fm * 1024);                         \
    _Pragma("unroll")                                                           \
    for (int fn = 0; fn < 4; ++fn)                                              \
        bf[fn] = *(const bf16x8*)(pB + SL + fn * 1024);                         \
    asm volatile("s_waitcnt lgkmcnt(0)" ::: "memory");                          \
    BAR();                                                                      \
    if ((t) + 2 < KT) STG((t) + 2);                                             \
    __builtin_amdgcn_s_setprio(1);                                              \
    _Pragma("unroll")                                                           \
    for (int fm = 0; fm < 4; ++fm)                                              \
        _Pragma("unroll")                                                       \
        for (int fn = 0; fn < 4; ++fn)                                          \
            acc[fm][fn] = __builtin_amdgcn_mfma_f32_16x16x32_bf16(              \
                af[fm], bf[fn], acc[fm][fn], 0, 0, 0);                          \
    __builtin_amdgcn_s_setprio(0);                                              \
    if ((t) + 2 < KT)      asm volatile("s_waitcnt vmcnt(4)" ::: "memory");     \
    else if ((t) + 1 < KT) asm volatile("s_waitcnt vmcnt(0)" ::: "memory");     \
    BAR();                                                                      \
} while (0)

    for (int tt = 0; tt < KT; tt += 2) {
        ITER(tt, 0);
        ITER(tt + 1, 1);
    }
#undef ITER
#undef STG

    // ---- epilogue: C/D layout col = lane&15, row = (lane>>4)*4 + reg ----
    const int cr = (l >> 4) * 4;
    const int cl = l & 15;
    #pragma unroll
    for (int fn = 0; fn < 4; ++fn) {
        const int col = tileN + wn * 64 + fn * 16 + cl;
        const float bs = bias[col];
        float gt = 0.f;
        if (EPI == 0) gt = gate[col];
        #pragma unroll
        for (int fm = 0; fm < 4; ++fm)
            #pragma unroll
            for (int r = 0; r < 4; ++r) {
                const int row = tileM + wm * 64 + fm * 16 + cr + r;
                float v = acc[fm][fn][r] + bs;
                if (EPI == 0) v = tanh_fast(v) * gt;
                C[(size_t)row * N + col] = f2bf(v);
            }
    }
}

// ---------------- row softmax + weighted sum + m_q_new ----------------
__global__ __launch_bounds__(256) void softmax_out(const u16* __restrict__ logits,
                                                   const float* __restrict__ hidden,
                                                   const float* __restrict__ m_q,
                                                   float* __restrict__ out,
                                                   int D, int R) {
    const int r = blockIdx.x;
    const int t = threadIdx.x;
    const int w = t >> 6, l = t & 63;
    const u16* lp = logits + (size_t)r * D + t * 8;
    const float* hp = hidden + (size_t)r * D + t * 8;

    bf16x8 lv = *(const bf16x8*)lp;
    float lf[8];
    #pragma unroll
    for (int j = 0; j < 8; ++j) lf[j] = bf2f((u16)lv[j]);
    float4 h0 = *(const float4*)hp;
    float4 h1 = *(const float4*)(hp + 4);
    float hv[8] = {h0.x, h0.y, h0.z, h0.w, h1.x, h1.y, h1.z, h1.w};

    float m = lf[0];
    #pragma unroll
    for (int j = 1; j < 8; ++j) m = fmaxf(m, lf[j]);
    #pragma unroll
    for (int o = 32; o >= 1; o >>= 1) m = fmaxf(m, __shfl_xor(m, o));

    __shared__ float red[8];
    if (l == 0) red[w] = m;
    __syncthreads();
    m = fmaxf(fmaxf(red[0], red[1]), fmaxf(red[2], red[3]));
    __syncthreads();

    float se = 0.f, sh = 0.f;
    #pragma unroll
    for (int j = 0; j < 8; ++j) {
        float e = __expf(lf[j] - m);
        se += e;
        sh += e * hv[j];
    }
    #pragma unroll
    for (int o = 32; o >= 1; o >>= 1) { se += __shfl_xor(se, o); sh += __shfl_xor(sh, o); }
    if (l == 0) { red[w] = se; red[4 + w] = sh; }
    __syncthreads();
    if (t == 0) {
        float SE = red[0] + red[1] + red[2] + red[3];
        float SH = red[4] + red[5] + red[6] + red[7];
        float o = SH / SE;
        out[r] = o;
        out[R + r] = m_q[r & (D - 1)] + o;
    }
}

extern "C" void kernel_launch(void* const* d_in, const int* in_sizes, int n_in,
                              void* d_out, int out_size, void* d_ws, size_t ws_size,
                              hipStream_t stream) {
    const float* hidden = (const float*)d_in[0];
    const float* m_q    = (const float*)d_in[1];
    const float* Wq     = (const float*)d_in[2];
    const float* bq     = (const float*)d_in[3];
    const float* Wm     = (const float*)d_in[4];
    const float* bm     = (const float*)d_in[5];
    const float* Wa     = (const float*)d_in[6];
    const float* ba     = (const float*)d_in[7];
    float* out = (float*)d_out;

    const int D = 2048;
    const int M = 16 * 2048;  // B*S = 32768

    char* ws = (char*)d_ws;
    size_t oH  = 0;
    size_t oS  = oH  + (size_t)M * D * 2;   // Sg bf16
    size_t oWq = oS  + (size_t)M * D * 2;
    size_t oWa = oWq + (size_t)D * D * 2;
    size_t oMq = oWa + (size_t)D * D * 2;
    size_t need = oMq + (size_t)D * sizeof(float);
    if (ws_size < need) return;

    u16* hbf    = (u16*)(ws + oH);
    u16* Sg     = (u16*)(ws + oS);
    u16* Wqb    = (u16*)(ws + oWq);
    u16* Wab    = (u16*)(ws + oWa);
    float* mq   = (float*)(ws + oMq);
    u16* logits = hbf;  // alias: hidden_bf16 dead after GEMM1

    cvt_f32_bf16<<<4096, 256, 0, stream>>>(hidden, hbf, M * D / 8);
    cvt_f32_bf16<<<1024, 256, 0, stream>>>(Wq, Wqb, D * D / 8);
    cvt_f32_bf16<<<1024, 256, 0, stream>>>(Wa, Wab, D * D / 8);
    mq_kernel<<<D / 4, 256, 0, stream>>>(Wm, m_q, bm, mq, D);

    dim3 grid(D / 128, M / 128);  // (16, 256) = 4096 blocks
    gemm_hi<0><<<grid, 256, 0, stream>>>(hbf, Wqb, bq, mq, Sg, M, D, D);
    gemm_hi<1><<<grid, 256, 0, stream>>>(Sg, Wab, ba, nullptr, logits, M, D, D);

    softmax_out<<<M, 256, 0, stream>>>(logits, hidden, m_q, out, D, M);
}

// Round 13
// 659.291 us; speedup vs baseline: 1.2927x; 1.2927x over previous
//
#include <hip/hip_runtime.h>

typedef unsigned short u16;
typedef short bf16x8 __attribute__((ext_vector_type(8)));
typedef u16 u16x8 __attribute__((ext_vector_type(8)));
typedef float f32x4 __attribute__((ext_vector_type(4)));

__device__ __forceinline__ float bf2f(u16 u) {
    union { unsigned u; float f; } c; c.u = ((unsigned)u) << 16; return c.f;
}
__device__ __forceinline__ u16 f2bf(float f) {
    union { float f; unsigned u; } c; c.f = f;
    unsigned r = c.u + 0x7FFFu + ((c.u >> 16) & 1u);
    return (u16)(r >> 16);
}
__device__ __forceinline__ float tanh_fast(float x) {
    float e = __expf(2.0f * x);
    return 1.0f - 2.0f / (e + 1.0f);
}
__device__ __forceinline__ void gll16(const void* g, void* l) {
    __builtin_amdgcn_global_load_lds((const __attribute__((address_space(1))) void*)g,
                                     (__attribute__((address_space(3))) void*)l, 16, 0, 0);
}

#define BAR() __builtin_amdgcn_s_barrier()

// ---------------- f32 -> bf16 convert, 8 elems/thread ----------------
__global__ __launch_bounds__(256) void cvt_f32_bf16(const float* __restrict__ src,
                                                    u16* __restrict__ dst, int n8) {
    int i = blockIdx.x * blockDim.x + threadIdx.x;
    int stride = gridDim.x * blockDim.x;
    for (; i < n8; i += stride) {
        const float4* s = (const float4*)(src + (size_t)i * 8);
        float4 a = s[0], b = s[1];
        u16x8 o;
        o[0] = f2bf(a.x); o[1] = f2bf(a.y); o[2] = f2bf(a.z); o[3] = f2bf(a.w);
        o[4] = f2bf(b.x); o[5] = f2bf(b.y); o[6] = f2bf(b.z); o[7] = f2bf(b.w);
        *(u16x8*)(dst + (size_t)i * 8) = o;
    }
}

// ---------------- mq = tanh(Wm @ m_q + bm), one wave per output ----------------
__global__ __launch_bounds__(256) void mq_kernel(const float* __restrict__ Wm,
                                                 const float* __restrict__ q,
                                                 const float* __restrict__ bm,
                                                 float* __restrict__ mq, int D) {
    int w = threadIdx.x >> 6, l = threadIdx.x & 63;
    int e = blockIdx.x * 4 + w;
    const float* wp = Wm + (size_t)e * D;
    float s = 0.f;
    for (int j = 0; j < D; j += 256) {
        float4 wv = *(const float4*)(wp + j + l * 4);
        float4 qv = *(const float4*)(q + j + l * 4);
        s += wv.x * qv.x + wv.y * qv.y + wv.z * qv.z + wv.w * qv.w;
    }
    #pragma unroll
    for (int o = 32; o >= 1; o >>= 1) s += __shfl_xor(s, o);
    if (l == 0) mq[e] = tanh_fast(s + bm[e]);
}

// ======== shared K-loop machinery (r9 structure, 256x256, BK=64, 8 waves) ========
#define GEMM_PREAMBLE()                                                          \
    __shared__ u16 sh[65536];                                                    \
    char* LDS = (char*)sh;                                                       \
    const int K2 = K * 2;                                                        \
    const int KT = K >> 6;                                                       \
    const int tid = threadIdx.x;                                                 \
    const int w = tid >> 6, l = tid & 63;                                        \
    const int wm = w >> 2, wn = w & 3;                                           \
    int orig = blockIdx.x + gridDim.x * blockIdx.y;                              \
    int nwg = gridDim.x * gridDim.y;                                             \
    int id = ((nwg & 7) == 0) ? ((orig & 7) * (nwg >> 3) + (orig >> 3)) : orig;  \
    const int tileN = (id % gridDim.x) * 256;                                    \
    const int tileM = (id / gridDim.x) * 256;                                    \
    const int r0 = (w * 2) * 8 + (l >> 3);                                       \
    const int r1 = (w * 2 + 1) * 8 + (l >> 3);                                   \
    const int cc = ((l & 7) ^ (l >> 3)) << 4;                                    \
    const char* srcA0 = (const char*)A + (size_t)(tileM + r0) * K2 + cc;         \
    const char* srcA1 = (const char*)A + (size_t)(tileM + r1) * K2 + cc;         \
    const char* srcB0 = (const char*)B + (size_t)(tileN + r0) * K2 + cc;         \
    const char* srcB1 = (const char*)B + (size_t)(tileN + r1) * K2 + cc;         \
    const int ldc0 = (w * 2) * 1024, ldc1 = (w * 2 + 1) * 1024;                  \
    const int sw = l & 7;                                                        \
    const int rowA = (wm * 64 + (l & 15)) * 128;                                 \
    const int rowB = (wn * 32 + (l & 15)) * 128;                                 \
    const int ck0 = (((l >> 4) ^ sw) << 4);                                      \
    const int ck1 = (((4 + (l >> 4)) ^ sw) << 4);                                \
    const char* pA0 = LDS + rowA + ck0;                                          \
    const char* pA1 = LDS + rowA + ck1;                                          \
    const char* pB0 = LDS + 65536 + rowB + ck0;                                  \
    const char* pB1 = LDS + 65536 + rowB + ck1;

#define STG_A(tk, h) do { size_t go = (size_t)(tk) * 128 + (size_t)(h) * 128 * K2; \
    int sb = ((((tk) & 1) * 2 + (h)) * 16384); \
    gll16(srcA0 + go, LDS + sb + ldc0); gll16(srcA1 + go, LDS + sb + ldc1); } while (0)
#define STG_B(tk, h) do { size_t go = (size_t)(tk) * 128 + (size_t)(h) * 128 * K2; \
    int sb = 65536 + ((((tk) & 1) * 2 + (h)) * 16384); \
    gll16(srcB0 + go, LDS + sb + ldc0); gll16(srcB1 + go, LDS + sb + ldc1); } while (0)

#define MFMA_CLUSTER(QM, QN, AF, BF)                                            \
    __builtin_amdgcn_s_setprio(1);                                              \
    _Pragma("unroll")                                                           \
    for (int fm = 0; fm < 4; ++fm)                                              \
        _Pragma("unroll")                                                       \
        for (int fn = 0; fn < 2; ++fn) {                                        \
            acc[QM][fm][QN][fn] = __builtin_amdgcn_mfma_f32_16x16x32_bf16(      \
                AF[fm][0], BF[fn][0], acc[QM][fm][QN][fn], 0, 0, 0);            \
            acc[QM][fm][QN][fn] = __builtin_amdgcn_mfma_f32_16x16x32_bf16(      \
                AF[fm][1], BF[fn][1], acc[QM][fm][QN][fn], 0, 0, 0);            \
        }                                                                       \
    __builtin_amdgcn_s_setprio(0);

#define ITER(t, P) do {                                                         \
    constexpr int A0O = (2 * (P)) * 16384;                                      \
    constexpr int A1O = (2 * (P) + 1) * 16384;                                  \
    bf16x8 af[4][2], b0[2][2], b1[2][2];                                        \
    _Pragma("unroll")                                                           \
    for (int fm = 0; fm < 4; ++fm) {                                            \
        af[fm][0] = *(const bf16x8*)(pA0 + A0O + fm * 2048);                    \
        af[fm][1] = *(const bf16x8*)(pA1 + A0O + fm * 2048);                    \
    }                                                                           \
    _Pragma("unroll")                                                           \
    for (int fn = 0; fn < 2; ++fn) {                                            \
        b0[fn][0] = *(const bf16x8*)(pB0 + A0O + fn * 2048);                    \
        b0[fn][1] = *(const bf16x8*)(pB1 + A0O + fn * 2048);                    \
    }                                                                           \
    if ((t) + 1 < KT) STG_A((t) + 1, 1);                                        \
    BAR();                                                                      \
    MFMA_CLUSTER(0, 0, af, b0)                                                  \
    BAR();                                                                      \
    _Pragma("unroll")                                                           \
    for (int fn = 0; fn < 2; ++fn) {                                            \
        b1[fn][0] = *(const bf16x8*)(pB0 + A1O + fn * 2048);                    \
        b1[fn][1] = *(const bf16x8*)(pB1 + A1O + fn * 2048);                    \
    }                                                                           \
    if ((t) + 1 < KT) STG_B((t) + 1, 1);                                        \
    BAR();                                                                      \
    MFMA_CLUSTER(0, 1, af, b1)                                                  \
    BAR();                                                                      \
    _Pragma("unroll")                                                           \
    for (int fm = 0; fm < 4; ++fm) {                                            \
        af[fm][0] = *(const bf16x8*)(pA0 + A1O + fm * 2048);                    \
        af[fm][1] = *(const bf16x8*)(pA1 + A1O + fm * 2048);                    \
    }                                                                           \
    if ((t) + 2 < KT) STG_A((t) + 2, 0);                                        \
    BAR();                                                                      \
    MFMA_CLUSTER(1, 0, af, b0)                                                  \
    BAR();                                                                      \
    if ((t) + 2 < KT) STG_B((t) + 2, 0);                                        \
    BAR();                                                                      \
    MFMA_CLUSTER(1, 1, af, b1)                                                  \
    if ((t) + 2 < KT) asm volatile("s_waitcnt vmcnt(4)" ::: "memory");          \
    else              asm volatile("s_waitcnt vmcnt(0)" ::: "memory");          \
    BAR();                                                                      \
} while (0)

#define GEMM_KLOOP()                                                            \
    STG_A(0, 0); STG_B(0, 0); STG_A(0, 1); STG_B(0, 1);                         \
    STG_A(1, 0); STG_B(1, 0);                                                   \
    asm volatile("s_waitcnt vmcnt(4)" ::: "memory");                            \
    BAR();                                                                      \
    for (int tt = 0; tt < KT; tt += 2) {                                        \
        ITER(tt, 0);                                                            \
        ITER(tt + 1, 1);                                                        \
    }

// ---------------- GEMM1: Sg = bf16( tanh(hbf@Wq^T + bq) * mq ) ----------------
__global__ __launch_bounds__(512, 2) void gemm8(const u16* __restrict__ A,
                                                const u16* __restrict__ B,
                                                const float* __restrict__ bias,
                                                const float* __restrict__ gate,
                                                u16* __restrict__ C,
                                                int M, int N, int K) {
    GEMM_PREAMBLE()
    f32x4 acc[2][4][2][2] = {};
    GEMM_KLOOP()

    const int cr = (l >> 4) * 4;
    const int cl = l & 15;
    #pragma unroll
    for (int qn = 0; qn < 2; ++qn)
        #pragma unroll
        for (int fn = 0; fn < 2; ++fn) {
            const int col = tileN + qn * 128 + wn * 32 + fn * 16 + cl;
            const float bs = bias[col];
            const float gt = gate[col];
            #pragma unroll
            for (int qm = 0; qm < 2; ++qm)
                #pragma unroll
                for (int fm = 0; fm < 4; ++fm)
                    #pragma unroll
                    for (int r = 0; r < 4; ++r) {
                        const int row = tileM + qm * 128 + wm * 64 + fm * 16 + cr + r;
                        float v = tanh_fast(acc[qm][fm][qn][fn][r] + bs) * gt;
                        C[(size_t)row * N + col] = f2bf(v);
                    }
        }
}

// ---- GEMM2 + partial softmax: per block (256 rows x 256 cols), write per-row
// (tile-max, tile-sum-exp, tile-sum-exp*h) partials to [M][N/256] arrays. ----
__global__ __launch_bounds__(512, 2) void gemm2p(const u16* __restrict__ A,   // Sg
                                                 const u16* __restrict__ B,   // Wa
                                                 const float* __restrict__ bias,
                                                 const u16* __restrict__ H,   // hbf
                                                 float* __restrict__ pmax,
                                                 float* __restrict__ pden,
                                                 float* __restrict__ pnum,
                                                 int M, int N, int K) {
    GEMM_PREAMBLE()
    f32x4 acc[2][4][2][2] = {};
    GEMM_KLOOP()

    // ---- partial-softmax epilogue (LDS reused; all K-loop LDS reads retired) ----
    const int cr = (l >> 4) * 4;
    const int cl = l & 15;
    const int NT = N >> 8;
    float* redA = (float*)LDS;              // [256][4] max
    float* redD = (float*)(LDS + 4096);     // [256][4] den
    float* redN = (float*)(LDS + 8192);     // [256][4] num
    float* rowmax = (float*)(LDS + 12288);  // [256]

    float bs[2][2];
    #pragma unroll
    for (int qn = 0; qn < 2; ++qn)
        #pragma unroll
        for (int fn = 0; fn < 2; ++fn)
            bs[qn][fn] = bias[tileN + qn * 128 + wn * 32 + fn * 16 + cl];

    // phase A: per-row max over this block's 256 cols
    #pragma unroll
    for (int qm = 0; qm < 2; ++qm)
        #pragma unroll
        for (int fm = 0; fm < 4; ++fm)
            #pragma unroll
            for (int rr = 0; rr < 4; ++rr) {
                float v = -1e30f;
                #pragma unroll
                for (int qn = 0; qn < 2; ++qn)
                    #pragma unroll
                    for (int fn = 0; fn < 2; ++fn)
                        v = fmaxf(v, acc[qm][fm][qn][fn][rr] + bs[qn][fn]);
                #pragma unroll
                for (int o = 8; o >= 1; o >>= 1) v = fmaxf(v, __shfl_xor(v, o));
                if (cl == 0)
                    redA[(qm * 128 + wm * 64 + fm * 16 + cr + rr) * 4 + wn] = v;
            }
    BAR();
    if (tid < 256)
        rowmax[tid] = fmaxf(fmaxf(redA[tid * 4], redA[tid * 4 + 1]),
                            fmaxf(redA[tid * 4 + 2], redA[tid * 4 + 3]));
    BAR();

    // phase B: den = sum exp, num = sum exp * h (h from bf16 H, L2/L3-resident slice)
    const u16* hbase = H + tileN + wn * 32 + cl;
    #pragma unroll
    for (int qm = 0; qm < 2; ++qm)
        #pragma unroll
        for (int fm = 0; fm < 4; ++fm)
            #pragma unroll
            for (int rr = 0; rr < 4; ++rr) {
                const int rl = qm * 128 + wm * 64 + fm * 16 + cr + rr;
                const float mm = rowmax[rl];
                const u16* hp = hbase + (size_t)(tileM + rl) * N;
                float ds = 0.f, ns = 0.f;
                #pragma unroll
                for (int qn = 0; qn < 2; ++qn)
                    #pragma unroll
                    for (int fn = 0; fn < 2; ++fn) {
                        float e = __expf(acc[qm][fm][qn][fn][rr] + bs[qn][fn] - mm);
                        ds += e;
                        ns += e * bf2f(hp[qn * 128 + fn * 16]);
                    }
                #pragma unroll
                for (int o = 8; o >= 1; o >>= 1) {
                    ds += __shfl_xor(ds, o);
                    ns += __shfl_xor(ns, o);
                }
                if (cl == 0) {
                    redD[rl * 4 + wn] = ds;
                    redN[rl * 4 + wn] = ns;
                }
            }
    BAR();
    if (tid < 256) {
        float d = redD[tid * 4] + redD[tid * 4 + 1] + redD[tid * 4 + 2] + redD[tid * 4 + 3];
        float n = redN[tid * 4] + redN[tid * 4 + 1] + redN[tid * 4 + 2] + redN[tid * 4 + 3];
        const size_t idx = (size_t)(tileM + tid) * NT + (tileN >> 8);
        pmax[idx] = rowmax[tid];
        pden[idx] = d;
        pnum[idx] = n;
    }
}

// ---- pass 2: combine 8 per-tile partials per row -> output, m_q_new ----
__global__ __launch_bounds__(256) void pass2(const float* __restrict__ pmax,
                                             const float* __restrict__ pden,
                                             const float* __restrict__ pnum,
                                             const float* __restrict__ m_q,
                                             float* __restrict__ out,
                                             int M, int D) {
    int rg = blockIdx.x * 256 + threadIdx.x;
    const float4* pm = (const float4*)(pmax + (size_t)rg * 8);
    const float4* pd = (const float4*)(pden + (size_t)rg * 8);
    const float4* pn = (const float4*)(pnum + (size_t)rg * 8);
    float4 m0 = pm[0], m1 = pm[1];
    float4 d0 = pd[0], d1 = pd[1];
    float4 n0 = pn[0], n1 = pn[1];
    float mv[8] = {m0.x, m0.y, m0.z, m0.w, m1.x, m1.y, m1.z, m1.w};
    float dv[8] = {d0.x, d0.y, d0.z, d0.w, d1.x, d1.y, d1.z, d1.w};
    float nv[8] = {n0.x, n0.y, n0.z, n0.w, n1.x, n1.y, n1.z, n1.w};
    float mg = mv[0];
    #pragma unroll
    for (int j = 1; j < 8; ++j) mg = fmaxf(mg, mv[j]);
    float den = 0.f, num = 0.f;
    #pragma unroll
    for (int j = 0; j < 8; ++j) {
        float e = __expf(mv[j] - mg);
        den += dv[j] * e;
        num += nv[j] * e;
    }
    float o = num / den;
    out[rg] = o;
    out[M + rg] = m_q[rg & (D - 1)] + o;
}

extern "C" void kernel_launch(void* const* d_in, const int* in_sizes, int n_in,
                              void* d_out, int out_size, void* d_ws, size_t ws_size,
                              hipStream_t stream) {
    const float* hidden = (const float*)d_in[0];
    const float* m_q    = (const float*)d_in[1];
    const float* Wq     = (const float*)d_in[2];
    const float* bq     = (const float*)d_in[3];
    const float* Wm     = (const float*)d_in[4];
    const float* bm     = (const float*)d_in[5];
    const float* Wa     = (const float*)d_in[6];
    const float* ba     = (const float*)d_in[7];
    float* out = (float*)d_out;

    const int D = 2048;
    const int M = 16 * 2048;  // B*S = 32768

    char* ws = (char*)d_ws;
    size_t oH  = 0;
    size_t oS  = oH  + (size_t)M * D * 2;   // Sg bf16
    size_t oWq = oS  + (size_t)M * D * 2;
    size_t oWa = oWq + (size_t)D * D * 2;
    size_t oMq = oWa + (size_t)D * D * 2;
    size_t oPM = oMq + (size_t)D * sizeof(float);
    size_t oPD = oPM + (size_t)M * 8 * sizeof(float);
    size_t oPN = oPD + (size_t)M * 8 * sizeof(float);
    size_t need = oPN + (size_t)M * 8 * sizeof(float);
    if (ws_size < need) return;

    u16* hbf    = (u16*)(ws + oH);
    u16* Sg     = (u16*)(ws + oS);
    u16* Wqb    = (u16*)(ws + oWq);
    u16* Wab    = (u16*)(ws + oWa);
    float* mq   = (float*)(ws + oMq);
    float* pM   = (float*)(ws + oPM);
    float* pD   = (float*)(ws + oPD);
    float* pN   = (float*)(ws + oPN);

    cvt_f32_bf16<<<4096, 256, 0, stream>>>(hidden, hbf, M * D / 8);
    cvt_f32_bf16<<<1024, 256, 0, stream>>>(Wq, Wqb, D * D / 8);
    cvt_f32_bf16<<<1024, 256, 0, stream>>>(Wa, Wab, D * D / 8);
    mq_kernel<<<D / 4, 256, 0, stream>>>(Wm, m_q, bm, mq, D);

    dim3 grid(D / 256, M / 256);  // (8, 128)
    gemm8<<<grid, 512, 0, stream>>>(hbf, Wqb, bq, mq, Sg, M, D, D);
    gemm2p<<<grid, 512, 0, stream>>>(Sg, Wab, ba, hbf, pM, pD, pN, M, D, D);

    pass2<<<M / 256, 256, 0, stream>>>(pM, pD, pN, m_q, out, M, D);
}